// Round 12
// baseline (73.889 us; speedup 1.0000x reference)
//
#include <hip/hip_runtime.h>
#include <cfloat>

// x: (B=256, T=150, J=25, 3) fp32 -> out: (B, J, 9) fp32
// Per frame: pairwise dists among 25 joints; per joint the 4 smallest
// non-self distances d1<=d2<=d3<=d4 feed [avg,std(ddof=1),min] for
// k=2,3,4; mean over T.
//
// Decomposition (verified R10): block = (batch, tile of 15 frames), grid 2560.
// Wave quarter (16 lanes) = one frame-slot; lane owns joint pair (2k, 2k+1):
// one ds_read_b128 of candidate i serves 4 frames x 2 joints.
// R11: final reduce fused -- block atomically adds its 225 scaled partials
// straight into out (zeroed by a memset node); no ws, no second kernel.
#define NB 256
#define NT 150
#define NJ 25
#define FPB 15              // frames per block
#define TILES (NT / FPB)    // 10
#define SLOTS 16            // frame slots (slot 15 = masked duplicate)
#define BLOCKSZ 256

#define FSQRT(x) __builtin_amdgcn_sqrtf(x)

// sorted ascending insert of v into (s0<=s1<=s2<=s3)
#define INS4(s0, s1, s2, s3, v)                                   \
    {                                                             \
        float m_;                                                 \
        m_ = fminf(s0, v); v = fmaxf(s0, v); s0 = m_;             \
        m_ = fminf(s1, v); v = fmaxf(s1, v); s1 = m_;             \
        m_ = fminf(s2, v); v = fmaxf(s2, v); s2 = m_;             \
        s3 = fminf(s3, v);                                        \
    }

// per-joint features from sorted squared dists r0..r3 -> f[7]={a2,s2,a3,s3,a4,s4,d1}
__device__ __forceinline__ void features(float r0, float r1, float r2, float r3,
                                         float* f) {
    const float d1 = FSQRT(r0), d2 = FSQRT(r1), d3 = FSQRT(r2), d4 = FSQRT(r3);
    const float rs2 = r0 + r1, rs3 = rs2 + r2, rs4 = rs3 + r3;
    const float s2 = d1 + d2, a2f = 0.5f * s2;
    const float s3 = s2 + d3, a3f = s3 * (1.0f / 3.0f);
    const float s4 = s3 + d4, a4f = 0.25f * s4;
    f[0] = a2f;
    f[1] = FSQRT(fmaxf(rs2 - 2.0f * a2f * a2f, 0.0f));
    f[2] = a3f;
    f[3] = FSQRT(fmaxf((rs3 - 3.0f * a3f * a3f) * 0.5f, 0.0f));
    f[4] = a4f;
    f[5] = FSQRT(fmaxf((rs4 - 4.0f * a4f * a4f) * (1.0f / 3.0f), 0.0f));
    f[6] = d1;
}

__global__ __launch_bounds__(BLOCKSZ, 8) void knn_feat(
        const float* __restrict__ x, float* __restrict__ out) {
    __shared__ float4 spos[SLOTS][NJ];     // 6.4 KB
    __shared__ float  red[4][16][14];      // 3.5 KB cross-wave reduce buffer

    const int tid  = threadIdx.x;
    const int wave = tid >> 6;
    const int lane = tid & 63;
    const int q    = (lane >> 4) & 3;      // quarter = frame-slot within wave
    const int k    = lane & 15;            // joint-pair owner
    const int slot = wave * 4 + q;         // 0..15
    const int jj0  = min(2 * k, NJ - 1);   // clamped pad chains; dropped at store
    const int jj1  = min(2 * k + 1, NJ - 1);

    const int blk   = blockIdx.x;          // [0, 2560)
    const int batch = blk / TILES;
    const int tile  = blk - batch * TILES;
    const int t0    = tile * FPB;

    // ---- stage 16 frame-slots (slot 15 clamped to frame 149) ----
#pragma unroll
    for (int turn = 0; turn < 2; ++turn) {
        const int t = tid + turn * BLOCKSZ;
        if (t < SLOTS * NJ) {
            const int fl = t / NJ;
            const int j  = t - fl * NJ;
            const int gf = min(t0 + fl, NT - 1);
            const float* s = x + (size_t)((batch * NT + gf) * NJ + j) * 3;
            spos[fl][j] = make_float4(s[0], s[1], s[2], 0.0f);
        }
    }
    __syncthreads();

    const float4 own0 = spos[slot][jj0];
    const float4 own1 = spos[slot][jj1];

    // two interleaved sorted-4 chains (joint pair) over squared distances;
    // the 25 candidate reads are shared by 4 frames x 2 joints per wave
    float a0 = FLT_MAX, a1 = FLT_MAX, a2 = FLT_MAX, a3 = FLT_MAX;
    float e0 = FLT_MAX, e1 = FLT_MAX, e2 = FLT_MAX, e3 = FLT_MAX;
#pragma unroll
    for (int i = 0; i < NJ; ++i) {
        const float4 c = spos[slot][i];
        float dx = c.x - own0.x, dy = c.y - own0.y, dz = c.z - own0.z;
        float d20 = dx * dx + dy * dy + dz * dz;
        dx = c.x - own1.x; dy = c.y - own1.y; dz = c.z - own1.z;
        float d21 = dx * dx + dy * dy + dz * dz;
        d20 = (i == jj0) ? FLT_MAX : d20;      // exclude self
        d21 = (i == jj1) ? FLT_MAX : d21;
        INS4(a0, a1, a2, a3, d20);
        INS4(e0, e1, e2, e3, d21);
    }

    float f0[7], f1[7];
    features(a0, a1, a2, a3, f0);
    features(e0, e1, e2, e3, f1);

    // slot validity (slot 15 is a masked duplicate; values finite so 0*x safe)
    const float vm = (slot < FPB) ? 1.0f : 0.0f;
    float acc0[7], acc1[7];
#pragma unroll
    for (int f = 0; f < 7; ++f) {
        acc0[f] = vm * f0[f];
        acc1[f] = vm * f1[f];
    }

    // ---- cross-quarter butterfly (sums the wave's 4 frame-slots per k) ----
#pragma unroll
    for (int f = 0; f < 7; ++f) {
        acc0[f] += __shfl_xor(acc0[f], 16, 64);
        acc0[f] += __shfl_xor(acc0[f], 32, 64);
        acc1[f] += __shfl_xor(acc1[f], 16, 64);
        acc1[f] += __shfl_xor(acc1[f], 32, 64);
    }
    if (lane < 16) {
#pragma unroll
        for (int f = 0; f < 7; ++f) {
            red[wave][k][f]     = acc0[f];
            red[wave][k][7 + f] = acc1[f];
        }
    }
    __syncthreads();

    // ---- cross-wave sum + fused final reduce: atomicAdd into out[b][j][f9] ----
    // (out zeroed by a memset node; 10 tile-partials accumulate per address)
    if (tid < NJ * 9) {
        const int j  = tid / 9;
        const int f9 = tid - j * 9;
        const int k2 = j >> 1;
        const int wh = j & 1;
        const int f7 = (f9 % 3 == 2) ? 6 : (f9 / 3) * 2 + (f9 % 3);
        const int idx = wh * 7 + f7;
        const float s = red[0][k2][idx] + red[1][k2][idx] +
                        red[2][k2][idx] + red[3][k2][idx];
        atomicAdd(out + (size_t)batch * (NJ * 9) + tid, s * (1.0f / (float)NT));
    }
}

extern "C" void kernel_launch(void* const* d_in, const int* in_sizes, int n_in,
                              void* d_out, int out_size, void* d_ws, size_t ws_size,
                              hipStream_t stream) {
    const float* x = (const float*)d_in[0];
    float* out = (float*)d_out;

    // out is poisoned before every replay -> zero it (atomic accumulation target)
    hipMemsetAsync(out, 0, (size_t)out_size * sizeof(float), stream);
    knn_feat<<<NB * TILES, BLOCKSZ, 0, stream>>>(x, out);
}

// Round 13
// 71.441 us; speedup vs baseline: 1.0343x; 1.0343x over previous
//
#include <hip/hip_runtime.h>
#include <cfloat>

// x: (B=256, T=150, J=25, 3) fp32 -> out: (B, J, 9) fp32
// Per frame: pairwise dists among 25 joints; per joint the 4 smallest
// non-self distances d1<=d2<=d3<=d4 feed [avg,std(ddof=1),min] for
// k=2,3,4; mean over T.
//
// Final (= R10, best measured 71.9 us): block = (batch, tile of 15 frames),
// grid 2560 (10 blocks/CU). Wave quarter (16 lanes) = one frame-slot; lane
// owns joint pair (2k, 2k+1): one ds_read_b128 serves 4 frames x 2 joints.
// Total is dominated by harness ws re-poison fill (~41 us @ 80% HBM peak);
// kernel-side ~20 us of which ~8 us is the VALU-issue floor.
#define NB 256
#define NT 150
#define NJ 25
#define FPB 15              // frames per block
#define TILES (NT / FPB)    // 10
#define SLOTS 16            // frame slots (slot 15 = masked duplicate)
#define BLOCKSZ 256

#define FSQRT(x) __builtin_amdgcn_sqrtf(x)

// sorted ascending insert of v into (s0<=s1<=s2<=s3)
#define INS4(s0, s1, s2, s3, v)                                   \
    {                                                             \
        float m_;                                                 \
        m_ = fminf(s0, v); v = fmaxf(s0, v); s0 = m_;             \
        m_ = fminf(s1, v); v = fmaxf(s1, v); s1 = m_;             \
        m_ = fminf(s2, v); v = fmaxf(s2, v); s2 = m_;             \
        s3 = fminf(s3, v);                                        \
    }

// per-joint features from sorted squared dists r0..r3 -> f[7]={a2,s2,a3,s3,a4,s4,d1}
__device__ __forceinline__ void features(float r0, float r1, float r2, float r3,
                                         float* f) {
    const float d1 = FSQRT(r0), d2 = FSQRT(r1), d3 = FSQRT(r2), d4 = FSQRT(r3);
    const float rs2 = r0 + r1, rs3 = rs2 + r2, rs4 = rs3 + r3;
    const float s2 = d1 + d2, a2f = 0.5f * s2;
    const float s3 = s2 + d3, a3f = s3 * (1.0f / 3.0f);
    const float s4 = s3 + d4, a4f = 0.25f * s4;
    f[0] = a2f;
    f[1] = FSQRT(fmaxf(rs2 - 2.0f * a2f * a2f, 0.0f));
    f[2] = a3f;
    f[3] = FSQRT(fmaxf((rs3 - 3.0f * a3f * a3f) * 0.5f, 0.0f));
    f[4] = a4f;
    f[5] = FSQRT(fmaxf((rs4 - 4.0f * a4f * a4f) * (1.0f / 3.0f), 0.0f));
    f[6] = d1;
}

__global__ __launch_bounds__(BLOCKSZ, 8) void knn_feat(
        const float* __restrict__ x, float* __restrict__ ws) {
    __shared__ float4 spos[SLOTS][NJ];     // 6.4 KB
    __shared__ float  red[4][16][14];      // 3.5 KB cross-wave reduce buffer

    const int tid  = threadIdx.x;
    const int wave = tid >> 6;
    const int lane = tid & 63;
    const int q    = (lane >> 4) & 3;      // quarter = frame-slot within wave
    const int k    = lane & 15;            // joint-pair owner
    const int slot = wave * 4 + q;         // 0..15
    const int jj0  = min(2 * k, NJ - 1);   // clamped pad chains; dropped at store
    const int jj1  = min(2 * k + 1, NJ - 1);

    const int blk   = blockIdx.x;          // [0, 2560)
    const int batch = blk / TILES;
    const int tile  = blk - batch * TILES;
    const int t0    = tile * FPB;

    // ---- stage 16 frame-slots (slot 15 clamped to frame 149) ----
#pragma unroll
    for (int turn = 0; turn < 2; ++turn) {
        const int t = tid + turn * BLOCKSZ;
        if (t < SLOTS * NJ) {
            const int fl = t / NJ;
            const int j  = t - fl * NJ;
            const int gf = min(t0 + fl, NT - 1);
            const float* s = x + (size_t)((batch * NT + gf) * NJ + j) * 3;
            spos[fl][j] = make_float4(s[0], s[1], s[2], 0.0f);
        }
    }
    __syncthreads();

    const float4 own0 = spos[slot][jj0];
    const float4 own1 = spos[slot][jj1];

    // two interleaved sorted-4 chains (joint pair) over squared distances;
    // the 25 candidate reads are shared by 4 frames x 2 joints per wave
    float a0 = FLT_MAX, a1 = FLT_MAX, a2 = FLT_MAX, a3 = FLT_MAX;
    float e0 = FLT_MAX, e1 = FLT_MAX, e2 = FLT_MAX, e3 = FLT_MAX;
#pragma unroll
    for (int i = 0; i < NJ; ++i) {
        const float4 c = spos[slot][i];
        float dx = c.x - own0.x, dy = c.y - own0.y, dz = c.z - own0.z;
        float d20 = dx * dx + dy * dy + dz * dz;
        dx = c.x - own1.x; dy = c.y - own1.y; dz = c.z - own1.z;
        float d21 = dx * dx + dy * dy + dz * dz;
        d20 = (i == jj0) ? FLT_MAX : d20;      // exclude self
        d21 = (i == jj1) ? FLT_MAX : d21;
        INS4(a0, a1, a2, a3, d20);
        INS4(e0, e1, e2, e3, d21);
    }

    float f0[7], f1[7];
    features(a0, a1, a2, a3, f0);
    features(e0, e1, e2, e3, f1);

    // slot validity (slot 15 is a masked duplicate; values finite so 0*x safe)
    const float vm = (slot < FPB) ? 1.0f : 0.0f;
    float acc0[7], acc1[7];
#pragma unroll
    for (int f = 0; f < 7; ++f) {
        acc0[f] = vm * f0[f];
        acc1[f] = vm * f1[f];
    }

    // ---- cross-quarter butterfly (sums the wave's 4 frame-slots per k) ----
#pragma unroll
    for (int f = 0; f < 7; ++f) {
        acc0[f] += __shfl_xor(acc0[f], 16, 64);
        acc0[f] += __shfl_xor(acc0[f], 32, 64);
        acc1[f] += __shfl_xor(acc1[f], 16, 64);
        acc1[f] += __shfl_xor(acc1[f], 32, 64);
    }
    if (lane < 16) {
#pragma unroll
        for (int f = 0; f < 7; ++f) {
            red[wave][k][f]     = acc0[f];
            red[wave][k][7 + f] = acc1[f];
        }
    }
    __syncthreads();

    // ---- cross-wave sum + scaled partial store: ws[blk][j][f7] ----
    if (tid < 16 * 14) {
        const int k2    = tid / 14;
        const int rest  = tid - k2 * 14;
        const int which = rest / 7;
        const int f     = rest - which * 7;
        const int j     = 2 * k2 + which;
        if (j < NJ) {
            const float s = red[0][k2][rest] + red[1][k2][rest] +
                            red[2][k2][rest] + red[3][k2][rest];
            ws[(size_t)blk * 175 + j * 7 + f] = s * (1.0f / (float)NT);
        }
    }
}

// out[b][j][f9] = sum over 10 tiles of ws[b*10+tile][j][f7]
__global__ __launch_bounds__(BLOCKSZ) void final_kernel(
        const float* __restrict__ ws, float* __restrict__ out) {
    const int o = blockIdx.x * blockDim.x + threadIdx.x;
    if (o >= NB * NJ * 9) return;
    const int f9 = o % 9;
    const int bj = o / 9;          // b*25 + j
    const int j  = bj % NJ;
    const int b  = bj / NJ;
    const int f7 = (f9 % 3 == 2) ? 6 : (f9 / 3) * 2 + (f9 % 3);
    const float* p = ws + (size_t)b * TILES * 175 + j * 7 + f7;
    float s = 0.0f;
#pragma unroll
    for (int t = 0; t < TILES; ++t) s += p[t * 175];
    out[o] = s;
}

extern "C" void kernel_launch(void* const* d_in, const int* in_sizes, int n_in,
                              void* d_out, int out_size, void* d_ws, size_t ws_size,
                              hipStream_t stream) {
    const float* x = (const float*)d_in[0];
    float* out = (float*)d_out;
    float* ws = (float*)d_ws;   // 2560 * 175 floats = 1.75 MB

    knn_feat<<<NB * TILES, BLOCKSZ, 0, stream>>>(x, ws);
    final_kernel<<<(NB * NJ * 9 + BLOCKSZ - 1) / BLOCKSZ, BLOCKSZ, 0, stream>>>(ws, out);
}